// Round 8
// baseline (15585.776 us; speedup 1.0000x reference)
//
#include <hip/hip_runtime.h>
#include <math.h>

// ESN reservoir: B=1, T=2048, I=8, R=4096, O=8.
// h_t = tanh(Win x_t + W h_{t-1}); y_t = Wout h_t + b.
//
// R8: counter-based readiness + one-shot data read.
//  - g_hist is pure f32 (no tags). Producers: system-scope write-through
//    store, vmcnt(0) drain, barrier, then ONE fire-and-forget system-scope
//    atomicAdd(&g_ctr,1) per WG. MALL is the serialization point: counter
//    value 256*t implies all h_{t-1} visible at MALL.
//  - Consumers: one thread/WG polls the single counter line (s_sleep
//    backoff; 256 pollers on 1 line vs R7's 64K pollers on 512 lines),
//    then all threads read the 16KB slice ONCE with 4 pipelined
//    global_load_dwordx4 sc0 sc1 (L2-bypass kills graph-replay staleness;
//    no retry loop -> no congestion collapse).
//  - g_ctr zeroed by init kernel each launch.
// Compute & reduction order bit-identical to R4..R7 (absmax 0.0078125).

#define T_STEPS 2048
#define R_DIM   4096
#define I_DIM   8
#define O_DIM   8
#define NWG     256
#define ROWS_PER_WG (R_DIM / NWG)   // 16
#define POOL_CAP 8192               // mean nnz/WG = 6554, ~21 sigma headroom
#define BLOCK    256

typedef float v4f __attribute__((ext_vector_type(4)));

__device__ float        g_hist[(size_t)T_STEPS * R_DIM];  // 32 MB
__device__ unsigned int g_ctr;

__global__ void esn_init_kernel() {
    if (threadIdx.x == 0)
        __hip_atomic_store(&g_ctr, 0u, __ATOMIC_RELAXED,
                           __HIP_MEMORY_SCOPE_SYSTEM);
}

__launch_bounds__(BLOCK, 1)
__global__ void esn_recur_kernel(const float* __restrict__ x,
                                 const float* __restrict__ Win,
                                 const float* __restrict__ W) {
    __shared__ uint2 s_pool[POOL_CAP];                // 64 KB (val bits, idx)
    __shared__ float s_h[R_DIM];                      // 16 KB
    __shared__ int   s_start[ROWS_PER_WG + 1];
    __shared__ int   s_cnt[ROWS_PER_WG];
    __shared__ float s_win[ROWS_PER_WG][I_DIM];

    const int wg   = blockIdx.x;
    const int tid  = threadIdx.x;
    const int lane = tid & 63;
    const int wave = tid >> 6;
    const int row0 = wg * ROWS_PER_WG;

    // ---------- one-time setup: compact 16 rows of W into LDS (order as R4) ----------
    for (int rr = wave; rr < ROWS_PER_WG; rr += 4) {
        const float* wrow = W + (size_t)(row0 + rr) * R_DIM;
        int cnt = 0;
        for (int base = 0; base < R_DIM; base += 64) {
            float v = wrow[base + lane];
            cnt += __popcll(__ballot(v != 0.0f));
        }
        if (lane == 0) s_cnt[rr] = cnt;
    }
    __syncthreads();
    if (tid == 0) {
        int acc = 0;
        for (int rr = 0; rr < ROWS_PER_WG; ++rr) {
            s_start[rr] = (acc < POOL_CAP) ? acc : POOL_CAP;
            acc += s_cnt[rr];
        }
        s_start[ROWS_PER_WG] = (acc < POOL_CAP) ? acc : POOL_CAP;
    }
    __syncthreads();
    for (int rr = wave; rr < ROWS_PER_WG; rr += 4) {
        const float* wrow = W + (size_t)(row0 + rr) * R_DIM;
        int off = s_start[rr];
        for (int base = 0; base < R_DIM; base += 64) {
            float v = wrow[base + lane];
            unsigned long long m = __ballot(v != 0.0f);
            int pre = __popcll(m & ((1ull << lane) - 1ull));
            if (v != 0.0f) {
                int pos = off + pre;
                if (pos < POOL_CAP) {
                    s_pool[pos].x = __float_as_uint(v);
                    s_pool[pos].y = base + lane;
                }
            }
            off += __popcll(m);
        }
    }
    if (tid < ROWS_PER_WG * I_DIM) {
        int rr = tid / I_DIM, c = tid % I_DIM;
        s_win[rr][c] = Win[(size_t)(row0 + rr) * I_DIM + c];
    }
    __syncthreads();

    const int row16 = tid >> 4;          // 0..15: which of my 16 rows
    const int sub   = tid & 15;          // 16 threads per row (as R4)
    const int start = s_start[row16];
    const int cnt   = s_start[row16 + 1] - start;

    // ---------- time loop ----------
    for (int t = 0; t < T_STEPS; ++t) {
        if (t > 0) {
            // readiness: all 256 WGs have published h_{t-1}
            if (tid == 0) {
                const unsigned target = (unsigned)t << 8;   // 256*t
                while (__hip_atomic_load(&g_ctr, __ATOMIC_RELAXED,
                                         __HIP_MEMORY_SCOPE_SYSTEM) < target)
                    __builtin_amdgcn_s_sleep(1);
            }
            __syncthreads();
            // one-shot bypass read of h_{t-1}: 16 KB via 4 dwordx4 sc0 sc1
            const v4f* src = (const v4f*)(g_hist + (size_t)(t - 1) * R_DIM);
            v4f r0, r1, r2, r3;
            const v4f* a0 = src + tid;
            const v4f* a1 = src + tid + 256;
            const v4f* a2 = src + tid + 512;
            const v4f* a3 = src + tid + 768;
            asm volatile(
                "global_load_dwordx4 %0, %4, off sc0 sc1\n\t"
                "global_load_dwordx4 %1, %5, off sc0 sc1\n\t"
                "global_load_dwordx4 %2, %6, off sc0 sc1\n\t"
                "global_load_dwordx4 %3, %7, off sc0 sc1\n\t"
                "s_waitcnt vmcnt(0)"
                : "=v"(r0), "=v"(r1), "=v"(r2), "=v"(r3)
                : "v"(a0), "v"(a1), "v"(a2), "v"(a3)
                : "memory");
            v4f* dst = (v4f*)s_h;
            dst[tid]       = r0;
            dst[tid + 256] = r1;
            dst[tid + 512] = r2;
            dst[tid + 768] = r3;
            __syncthreads();
        }

        // sparse row-dot: identical order to R4..R7 (16-lane groups, stride 16)
        float acc = 0.0f;
        if (t > 0) {
            for (int e = start + sub; e < start + cnt; e += 16) {
                uint2 p = s_pool[e];
                acc += __uint_as_float(p.x) * s_h[p.y];
            }
        }
        acc += __shfl_xor(acc, 8, 16);
        acc += __shfl_xor(acc, 4, 16);
        acc += __shfl_xor(acc, 2, 16);
        acc += __shfl_xor(acc, 1, 16);

        if (sub == 0) {
            const float* xt = x + (size_t)t * I_DIM;
            float a = acc;
            #pragma unroll
            for (int c = 0; c < I_DIM; ++c) a += s_win[row16][c] * xt[c];
            float h = tanhf(a);
            // write-through to coherence point (MALL)
            __hip_atomic_store(&g_hist[(size_t)t * R_DIM + row0 + row16], h,
                               __ATOMIC_RELAXED, __HIP_MEMORY_SCOPE_SYSTEM);
        }
        // release: drain own stores (acked at MALL), join WG, then count up
        asm volatile("s_waitcnt vmcnt(0)" ::: "memory");
        __syncthreads();
        if (tid == 0) {
            (void)__hip_atomic_fetch_add(&g_ctr, 1u, __ATOMIC_RELAXED,
                                         __HIP_MEMORY_SCOPE_SYSTEM);
        }
    }
}

// y_t = Wout h_t + b, one wave per timestep; accumulation order as R4..R7.
__global__ void esn_out_kernel(const float* __restrict__ Wout_w,
                               const float* __restrict__ Wout_b,
                               float* __restrict__ out) {
    const int t = blockIdx.x;
    const int lane = threadIdx.x;  // 64 threads
    const float* hp = g_hist + (size_t)t * R_DIM;
    float acc[O_DIM];
    #pragma unroll
    for (int o = 0; o < O_DIM; ++o) acc[o] = 0.0f;
    for (int i = lane; i < R_DIM; i += 256) {   // 16 iters, 4 indep loads each
        float h0 = __hip_atomic_load(hp + i,       __ATOMIC_RELAXED, __HIP_MEMORY_SCOPE_SYSTEM);
        float h1 = __hip_atomic_load(hp + i + 64,  __ATOMIC_RELAXED, __HIP_MEMORY_SCOPE_SYSTEM);
        float h2 = __hip_atomic_load(hp + i + 128, __ATOMIC_RELAXED, __HIP_MEMORY_SCOPE_SYSTEM);
        float h3 = __hip_atomic_load(hp + i + 192, __ATOMIC_RELAXED, __HIP_MEMORY_SCOPE_SYSTEM);
        #pragma unroll
        for (int o = 0; o < O_DIM; ++o) acc[o] += h0 * Wout_w[(size_t)o * R_DIM + i];
        #pragma unroll
        for (int o = 0; o < O_DIM; ++o) acc[o] += h1 * Wout_w[(size_t)o * R_DIM + i + 64];
        #pragma unroll
        for (int o = 0; o < O_DIM; ++o) acc[o] += h2 * Wout_w[(size_t)o * R_DIM + i + 128];
        #pragma unroll
        for (int o = 0; o < O_DIM; ++o) acc[o] += h3 * Wout_w[(size_t)o * R_DIM + i + 192];
    }
    #pragma unroll
    for (int o = 0; o < O_DIM; ++o) {
        float a = acc[o];
        a += __shfl_xor(a, 32);
        a += __shfl_xor(a, 16);
        a += __shfl_xor(a, 8);
        a += __shfl_xor(a, 4);
        a += __shfl_xor(a, 2);
        a += __shfl_xor(a, 1);
        if (lane == 0) out[(size_t)t * O_DIM + o] = a + Wout_b[o];
    }
}

extern "C" void kernel_launch(void* const* d_in, const int* in_sizes, int n_in,
                              void* d_out, int out_size, void* d_ws, size_t ws_size,
                              hipStream_t stream) {
    const float* x    = (const float*)d_in[0];   // [1,2048,8]
    const float* Win  = (const float*)d_in[1];   // [4096,8]
    const float* W    = (const float*)d_in[2];   // [4096,4096]
    const float* Ww   = (const float*)d_in[3];   // [8,4096]
    const float* Wb   = (const float*)d_in[4];   // [8]
    float* out = (float*)d_out;                  // [1,2048,8]

    hipLaunchKernelGGL(esn_init_kernel, dim3(1), dim3(64), 0, stream);

    void* args[] = { (void*)&x, (void*)&Win, (void*)&W };
    hipLaunchCooperativeKernel((void*)esn_recur_kernel, dim3(NWG), dim3(BLOCK),
                               args, 0, stream);

    hipLaunchKernelGGL(esn_out_kernel, dim3(T_STEPS), dim3(64), 0, stream,
                       Ww, Wb, out);
}

// Round 10
// 8808.494 us; speedup vs baseline: 1.7694x; 1.7694x over previous
//
#include <hip/hip_runtime.h>
#include <math.h>

// ESN reservoir: B=1, T=2048, I=8, R=4096, O=8.
// h_t = tanh(Win x_t + W h_{t-1}); y_t = Wout h_t + b.
//
// R10: halve the participant count. 128 WGs x 512 threads, 32 rows/WG,
// sparse W pool (~128 KB) + s_h (16 KB) in LDS (~145 KB of 160 KB/CU).
// Sync is R4's proven SYMMETRIC flag scheme (stable, no outliers), but:
//  - each WG's flag on its OWN 128-B line (128 pollers/line vs R4 4K/line)
//  - s_sleep backoff in the poll loop
//  - h exchange: producer system-scope write-through store + vmcnt drain +
//    barrier + flag store; consumer one-shot 2x global_load_dwordx4 sc0 sc1
// All congestion terms scale with NWG: poll aggregate /4, broadcast bytes /2,
// straggler set /2. No retry loop / RMW / aggregator -> no collapse modes.
// NUMERICS BIT-IDENTICAL to R4..R8: still 16 threads/row, same stride-16
// entry order, same shfl tree, same Win/tanh, same out-kernel.

#define T_STEPS 2048
#define R_DIM   4096
#define I_DIM   8
#define O_DIM   8
#define NWG     128
#define ROWS_PER_WG (R_DIM / NWG)   // 32
#define POOL_CAP 16384              // mean nnz/WG = 13107, ~30 sigma headroom
#define BLOCK    512                // 16 threads/row x 32 rows

typedef float v4f __attribute__((ext_vector_type(4)));

__device__ float        g_hist[(size_t)T_STEPS * R_DIM];  // 32 MB
__device__ unsigned int g_flag[NWG * 32];                 // one 128-B line per WG

__global__ void esn_init_kernel() {
    for (int i = threadIdx.x; i < NWG * 32; i += blockDim.x)
        __hip_atomic_store(&g_flag[i], 0u, __ATOMIC_RELAXED,
                           __HIP_MEMORY_SCOPE_SYSTEM);
}

__launch_bounds__(BLOCK, 1)
__global__ void esn_recur_kernel(const float* __restrict__ x,
                                 const float* __restrict__ Win,
                                 const float* __restrict__ W) {
    __shared__ uint2 s_pool[POOL_CAP];                // 128 KB (val bits, idx)
    __shared__ float s_h[R_DIM];                      // 16 KB
    __shared__ int   s_start[ROWS_PER_WG + 1];
    __shared__ int   s_cnt[ROWS_PER_WG];
    __shared__ float s_win[ROWS_PER_WG][I_DIM];

    const int wg   = blockIdx.x;
    const int tid  = threadIdx.x;
    const int lane = tid & 63;
    const int wave = tid >> 6;          // 0..7
    const int row0 = wg * ROWS_PER_WG;

    // ---------- one-time setup: compact 32 rows of W into LDS ----------
    // (per-row entry order identical to R4: ballot-compaction in column order)
    for (int rr = wave; rr < ROWS_PER_WG; rr += 8) {
        const float* wrow = W + (size_t)(row0 + rr) * R_DIM;
        int cnt = 0;
        for (int base = 0; base < R_DIM; base += 64) {
            float v = wrow[base + lane];
            cnt += __popcll(__ballot(v != 0.0f));
        }
        if (lane == 0) s_cnt[rr] = cnt;
    }
    __syncthreads();
    if (tid == 0) {
        int acc = 0;
        for (int rr = 0; rr < ROWS_PER_WG; ++rr) {
            s_start[rr] = (acc < POOL_CAP) ? acc : POOL_CAP;
            acc += s_cnt[rr];
        }
        s_start[ROWS_PER_WG] = (acc < POOL_CAP) ? acc : POOL_CAP;
    }
    __syncthreads();
    for (int rr = wave; rr < ROWS_PER_WG; rr += 8) {
        const float* wrow = W + (size_t)(row0 + rr) * R_DIM;
        int off = s_start[rr];
        for (int base = 0; base < R_DIM; base += 64) {
            float v = wrow[base + lane];
            unsigned long long m = __ballot(v != 0.0f);
            int pre = __popcll(m & ((1ull << lane) - 1ull));
            if (v != 0.0f) {
                int pos = off + pre;
                if (pos < POOL_CAP) {
                    s_pool[pos].x = __float_as_uint(v);
                    s_pool[pos].y = base + lane;
                }
            }
            off += __popcll(m);
        }
    }
    if (tid < ROWS_PER_WG * I_DIM) {
        int rr = tid / I_DIM, c = tid % I_DIM;
        s_win[rr][c] = Win[(size_t)(row0 + rr) * I_DIM + c];
    }
    __syncthreads();

    const int row16 = tid >> 4;          // 0..31: which of my 32 rows
    const int sub   = tid & 15;          // 16 threads per row (as R4)
    const int start = s_start[row16];
    const int cnt   = s_start[row16 + 1] - start;

    // ---------- time loop ----------
    for (int t = 0; t < T_STEPS; ++t) {
        if (t > 0) {
            const unsigned ut = (unsigned)t;
            // symmetric readiness: thread i (<128) polls WG i's own flag line
            if (tid < NWG) {
                while (__hip_atomic_load(&g_flag[tid << 5], __ATOMIC_RELAXED,
                                         __HIP_MEMORY_SCOPE_SYSTEM) < ut)
                    __builtin_amdgcn_s_sleep(2);
            }
            __syncthreads();
            // one-shot bypass read of h_{t-1}: 16 KB via 2 dwordx4 per thread
            const v4f* src = (const v4f*)(g_hist + (size_t)(t - 1) * R_DIM);
            v4f r0, r1;
            const v4f* a0 = src + tid;
            const v4f* a1 = src + tid + 512;
            asm volatile(
                "global_load_dwordx4 %0, %2, off sc0 sc1\n\t"
                "global_load_dwordx4 %1, %3, off sc0 sc1\n\t"
                "s_waitcnt vmcnt(0)"
                : "=v"(r0), "=v"(r1)
                : "v"(a0), "v"(a1)
                : "memory");
            v4f* dst = (v4f*)s_h;
            dst[tid]       = r0;
            dst[tid + 512] = r1;
            __syncthreads();
        }

        // sparse row-dot: identical per-row order to R4..R8 (16 lanes, stride 16)
        float acc = 0.0f;
        if (t > 0) {
            for (int e = start + sub; e < start + cnt; e += 16) {
                uint2 p = s_pool[e];
                acc += __uint_as_float(p.x) * s_h[p.y];
            }
        }
        acc += __shfl_xor(acc, 8, 16);
        acc += __shfl_xor(acc, 4, 16);
        acc += __shfl_xor(acc, 2, 16);
        acc += __shfl_xor(acc, 1, 16);

        if (sub == 0) {
            const float* xt = x + (size_t)t * I_DIM;
            float a = acc;
            #pragma unroll
            for (int c = 0; c < I_DIM; ++c) a += s_win[row16][c] * xt[c];
            float h = tanhf(a);
            // write-through to coherence point (MALL)
            __hip_atomic_store(&g_hist[(size_t)t * R_DIM + row0 + row16], h,
                               __ATOMIC_RELAXED, __HIP_MEMORY_SCOPE_SYSTEM);
        }
        // release: drain own stores (acked at MALL), join WG, publish flag
        asm volatile("s_waitcnt vmcnt(0)" ::: "memory");
        __syncthreads();
        if (tid == 0)
            __hip_atomic_store(&g_flag[wg << 5], (unsigned)(t + 1),
                               __ATOMIC_RELAXED, __HIP_MEMORY_SCOPE_SYSTEM);
    }
}

// y_t = Wout h_t + b, one wave per timestep; accumulation order as R4..R9.
__global__ void esn_out_kernel(const float* __restrict__ Wout_w,
                               const float* __restrict__ Wout_b,
                               float* __restrict__ out) {
    const int t = blockIdx.x;
    const int lane = threadIdx.x;  // 64 threads
    const float* hp = g_hist + (size_t)t * R_DIM;
    float acc[O_DIM];
    #pragma unroll
    for (int o = 0; o < O_DIM; ++o) acc[o] = 0.0f;
    for (int i = lane; i < R_DIM; i += 256) {   // 16 iters, 4 indep loads each
        float h0 = __hip_atomic_load(hp + i,       __ATOMIC_RELAXED, __HIP_MEMORY_SCOPE_SYSTEM);
        float h1 = __hip_atomic_load(hp + i + 64,  __ATOMIC_RELAXED, __HIP_MEMORY_SCOPE_SYSTEM);
        float h2 = __hip_atomic_load(hp + i + 128, __ATOMIC_RELAXED, __HIP_MEMORY_SCOPE_SYSTEM);
        float h3 = __hip_atomic_load(hp + i + 192, __ATOMIC_RELAXED, __HIP_MEMORY_SCOPE_SYSTEM);
        #pragma unroll
        for (int o = 0; o < O_DIM; ++o) acc[o] += h0 * Wout_w[(size_t)o * R_DIM + i];
        #pragma unroll
        for (int o = 0; o < O_DIM; ++o) acc[o] += h1 * Wout_w[(size_t)o * R_DIM + i + 64];
        #pragma unroll
        for (int o = 0; o < O_DIM; ++o) acc[o] += h2 * Wout_w[(size_t)o * R_DIM + i + 128];
        #pragma unroll
        for (int o = 0; o < O_DIM; ++o) acc[o] += h3 * Wout_w[(size_t)o * R_DIM + i + 192];
    }
    #pragma unroll
    for (int o = 0; o < O_DIM; ++o) {
        float a = acc[o];
        a += __shfl_xor(a, 32);
        a += __shfl_xor(a, 16);
        a += __shfl_xor(a, 8);
        a += __shfl_xor(a, 4);
        a += __shfl_xor(a, 2);
        a += __shfl_xor(a, 1);
        if (lane == 0) out[(size_t)t * O_DIM + o] = a + Wout_b[o];
    }
}

extern "C" void kernel_launch(void* const* d_in, const int* in_sizes, int n_in,
                              void* d_out, int out_size, void* d_ws, size_t ws_size,
                              hipStream_t stream) {
    const float* x    = (const float*)d_in[0];   // [1,2048,8]
    const float* Win  = (const float*)d_in[1];   // [4096,8]
    const float* W    = (const float*)d_in[2];   // [4096,4096]
    const float* Ww   = (const float*)d_in[3];   // [8,4096]
    const float* Wb   = (const float*)d_in[4];   // [8]
    float* out = (float*)d_out;                  // [1,2048,8]

    hipLaunchKernelGGL(esn_init_kernel, dim3(1), dim3(256), 0, stream);

    void* args[] = { (void*)&x, (void*)&Win, (void*)&W };
    hipLaunchCooperativeKernel((void*)esn_recur_kernel, dim3(NWG), dim3(BLOCK),
                               args, 0, stream);

    hipLaunchKernelGGL(esn_out_kernel, dim3(T_STEPS), dim3(64), 0, stream,
                       Ww, Wb, out);
}